// Round 1
// baseline (3862.485 us; speedup 1.0000x reference)
//
#include <hip/hip_runtime.h>
#include <hip/hip_bf16.h>

// ALSH Conv: hash-table init + vote + mask + masked 3x3 conv.
// x: [32,64,128,128] f32, kernels: [256,64,3,3] f32, a: [8,67,3,3] f32, b: [8] f32
// out: [32,256,128,128] f32. R=4, U=0.99, table=512.

#define NCH 64
#define OCH 256
#define HNUM 8
#define IMG 128
#define TSZ 512
#define KROW 576      // 64*9
#define AROW 603      // 67*9
#define MPOW 27

// ---------------- K1: row norms, scale, zero counts ----------------
__global__ __launch_bounds__(256) void k_norms(
    const float* __restrict__ kernels, float* __restrict__ norms,
    float* __restrict__ scale_out, int* __restrict__ counts) {
  int o = threadIdx.x;
  const float* row = kernels + (size_t)o * KROW;
  float s = 0.f;
  for (int i = 0; i < KROW; i++) { float v = row[i]; s = fmaf(v, v, s); }
  float nrm = sqrtf(s);
  norms[o] = nrm;
  __shared__ float red[256];
  red[o] = nrm;
  __syncthreads();
  for (int st = 128; st > 0; st >>= 1) {
    if (o < st) red[o] = fmaxf(red[o], red[o + st]);
    __syncthreads();
  }
  if (o == 0) scale_out[0] = 0.99f / red[0];
  for (int i = o; i < HNUM * TSZ; i += 256) counts[i] = 0;
}

// ---------------- K2: kernel buckets under each hash ----------------
__global__ __launch_bounds__(256) void k_table(
    const float* __restrict__ kernels, const float* __restrict__ a,
    const float* __restrict__ b, const float* __restrict__ scale_p,
    int* __restrict__ kbuck) {
  int h = blockIdx.x;     // 0..7
  int o = threadIdx.x;    // 0..255
  float scale = *scale_p;
  const float* ar = a + (size_t)h * AROW;
  const float* kr = kernels + (size_t)o * KROW;
  float dot = 0.f, s2 = 0.f;
  for (int i = 0; i < KROW; i++) {
    float sv = scale * kr[i];
    dot = fmaf(ar[i], sv, dot);
    s2 = fmaf(sv, sv, s2);
  }
  float p = sqrtf(s2);                 // sn = ||scaled row||
  for (int j = 1; j <= MPOW; j++) {    // powers sn^(2^j)
    p = p * p;
    dot = fmaf(ar[KROW - 1 + j], p, dot);
  }
  float v = floorf((dot + b[h]) * 0.25f);
  v = fabsf(fmodf(v, (float)TSZ));
  kbuck[h * OCH + o] = (int)v;
}

// ---------------- K3: vote conv + histogram ----------------
__global__ __launch_bounds__(256) void k_vote(
    const float* __restrict__ x, const float* __restrict__ a,
    const float* __restrict__ b, int* __restrict__ counts) {
  int tid = threadIdx.x;
  int tx0 = blockIdx.x << 4, ty0 = blockIdx.y << 4;
  int n = blockIdx.z;
  int lx = tid & 15, ly = tid >> 4;

  __shared__ float tile_s[18 * 18];
  __shared__ int hist[HNUM * TSZ];
  for (int i = tid; i < HNUM * TSZ; i += 256) hist[i] = 0;

  float acc[HNUM] = {0, 0, 0, 0, 0, 0, 0, 0};
  const float* xn = x + (size_t)n * NCH * (IMG * IMG);

  for (int c = 0; c < 67; c++) {
    __syncthreads();
    for (int i = tid; i < 324; i += 256) {
      int yy = ty0 + i / 18 - 1;
      int xx = tx0 + i % 18 - 1;
      float v = 0.0f;
      if ((unsigned)yy < (unsigned)IMG && (unsigned)xx < (unsigned)IMG)
        v = (c < NCH) ? xn[(size_t)c * (IMG * IMG) + yy * IMG + xx] : 0.5f;
      tile_s[i] = v;
    }
    __syncthreads();
    float t[9];
#pragma unroll
    for (int dy = 0; dy < 3; dy++)
#pragma unroll
      for (int dx = 0; dx < 3; dx++)
        t[dy * 3 + dx] = tile_s[(ly + dy) * 18 + lx + dx];
#pragma unroll
    for (int h = 0; h < HNUM; h++) {
      const float* ww = a + (size_t)(h * 67 + c) * 9;  // uniform -> s_load
      float s = acc[h];
#pragma unroll
      for (int k = 0; k < 9; k++) s = fmaf(t[k], ww[k], s);
      acc[h] = s;
    }
  }
  __syncthreads();
#pragma unroll
  for (int h = 0; h < HNUM; h++) {
    float v = floorf((acc[h] + b[h]) * 0.25f);
    v = fabsf(fmodf(v, (float)TSZ));
    atomicAdd(&hist[(h << 9) + (int)v], 1);
  }
  __syncthreads();
  for (int i = tid; i < HNUM * TSZ; i += 256) {
    int c = hist[i];
    if (c) atomicAdd(&counts[i], c);
  }
}

// ---------------- K4: argmax per hash + mask + compaction ----------------
__global__ __launch_bounds__(512) void k_mask(
    const int* __restrict__ counts, const int* __restrict__ kbuck,
    int* __restrict__ mask, int* __restrict__ act, int* __restrict__ nact,
    int* __restrict__ inact, int* __restrict__ ninact) {
  int tid = threadIdx.x;
  __shared__ int sv[HNUM];
  int h = tid >> 6, lane = tid & 63;
  // argmax with first-max tie-break: key = count*1024 + (511 - idx), count<2^20
  int best = -1;
  for (int i = lane; i < TSZ; i += 64) {
    int key = (counts[h * TSZ + i] << 10) | (TSZ - 1 - i);
    if (key > best) best = key;
  }
  for (int off = 32; off > 0; off >>= 1) {
    int other = __shfl_xor(best, off);
    if (other > best) best = other;
  }
  if (lane == 0) sv[h] = (TSZ - 1) - (best & 1023);
  __syncthreads();
  __shared__ int smask[OCH];
  if (tid < OCH) {
    int m = 0;
    for (int hh = 0; hh < HNUM; hh++) {
      int kv = kbuck[hh * OCH + tid];
#pragma unroll
      for (int j = 0; j < HNUM; j++) m |= (kv == sv[j]) ? 1 : 0;
    }
    smask[tid] = m;
    mask[tid] = m;
  }
  __syncthreads();
  if (tid == 0) {
    int na = 0, ni = 0;
    for (int o = 0; o < OCH; o++) {
      if (smask[o]) act[na++] = o;
      else inact[ni++] = o;
    }
    for (int i = na; i < OCH; i++) act[i] = 0;    // pad: safe garbage
    for (int i = ni; i < OCH; i++) inact[i] = 0;
    *nact = na;
    *ninact = ni;
  }
}

// ---------------- K5: main conv over compacted active channels ----------------
__global__ __launch_bounds__(256) void k_conv(
    const float* __restrict__ x, const float* __restrict__ w,
    const int* __restrict__ act, const int* __restrict__ nact_p,
    const int* __restrict__ inact, const int* __restrict__ ninact_p,
    float* __restrict__ out) {
  int tid = threadIdx.x;
  int slot = blockIdx.x;   // 0..31 (8 channels per slot, compacted)
  int tile = blockIdx.y;   // 0..63
  int n = blockIdx.z;      // 0..31
  int tx0 = (tile & 7) << 4, ty0 = (tile >> 3) << 4;
  int lx = tid & 15, ly = tid >> 4;
  int ox = tx0 + lx, oy = ty0 + ly;

  __shared__ float tile_s[18 * 18];
  __shared__ int s_hdr[18];  // [0]=cnta [1]=cnti [2..9]=act [10..17]=inact

  if (tid == 0) {
    int na = *nact_p, ni = *ninact_p;
    int ca = na - slot * 8; ca = ca < 0 ? 0 : (ca > 8 ? 8 : ca);
    int ci = ni - slot * 8; ci = ci < 0 ? 0 : (ci > 8 ? 8 : ci);
    s_hdr[0] = ca; s_hdr[1] = ci;
  }
  if (tid < 8) {
    s_hdr[2 + tid] = act[slot * 8 + tid];
    s_hdr[10 + tid] = inact[slot * 8 + tid];
  }
  __syncthreads();
  int cnta = s_hdr[0], cnti = s_hdr[1];

  size_t pix = (size_t)oy * IMG + ox;
  float* outn = out + (size_t)n * OCH * (IMG * IMG);
  for (int i = 0; i < cnti; i++)
    outn[(size_t)s_hdr[10 + i] * (IMG * IMG) + pix] = 0.0f;
  if (cnta == 0) return;

  // wave-uniform weight bases -> scalar loads in the hot loop
  const float* wb[8];
#pragma unroll
  for (int i = 0; i < 8; i++) {
    int o = __builtin_amdgcn_readfirstlane(s_hdr[2 + i]);
    wb[i] = w + (size_t)o * KROW;
  }

  float acc[8] = {0, 0, 0, 0, 0, 0, 0, 0};
  const float* xn = x + (size_t)n * NCH * (IMG * IMG);

  for (int c = 0; c < NCH; c++) {
    const float* xc = xn + (size_t)c * (IMG * IMG);
    __syncthreads();
    for (int i = tid; i < 324; i += 256) {
      int yy = ty0 + i / 18 - 1;
      int xx = tx0 + i % 18 - 1;
      float v = 0.0f;
      if ((unsigned)yy < (unsigned)IMG && (unsigned)xx < (unsigned)IMG)
        v = xc[yy * IMG + xx];
      tile_s[i] = v;
    }
    __syncthreads();
    float t[9];
#pragma unroll
    for (int dy = 0; dy < 3; dy++)
#pragma unroll
      for (int dx = 0; dx < 3; dx++)
        t[dy * 3 + dx] = tile_s[(ly + dy) * 18 + lx + dx];
#pragma unroll
    for (int i = 0; i < 8; i++) {
      const float* ww = wb[i] + c * 9;
      float s = acc[i];
#pragma unroll
      for (int k = 0; k < 9; k++) s = fmaf(t[k], ww[k], s);
      acc[i] = s;
    }
  }
  for (int i = 0; i < cnta; i++)
    outn[(size_t)s_hdr[2 + i] * (IMG * IMG) + pix] = acc[i];
}

extern "C" void kernel_launch(void* const* d_in, const int* in_sizes, int n_in,
                              void* d_out, int out_size, void* d_ws, size_t ws_size,
                              hipStream_t stream) {
  const float* x = (const float*)d_in[0];
  const float* kernels = (const float*)d_in[1];
  const float* a = (const float*)d_in[2];
  const float* b = (const float*)d_in[3];
  float* out = (float*)d_out;

  char* ws = (char*)d_ws;
  float* norms  = (float*)(ws + 0);        // 1024 B
  float* scale  = (float*)(ws + 1024);     // 4 B
  int* kbuck    = (int*)(ws + 2048);       // 8192 B
  int* counts   = (int*)(ws + 10240);      // 16384 B
  int* mask     = (int*)(ws + 26624);      // 1024 B
  int* act      = (int*)(ws + 27648);      // 1024 B
  int* nact     = (int*)(ws + 28672);      // 4 B
  int* inact    = (int*)(ws + 29696);      // 1024 B
  int* ninact   = (int*)(ws + 30720);      // 4 B

  k_norms<<<1, 256, 0, stream>>>(kernels, norms, scale, counts);
  k_table<<<HNUM, 256, 0, stream>>>(kernels, a, b, scale, kbuck);
  k_vote<<<dim3(8, 8, 32), 256, 0, stream>>>(x, a, b, counts);
  k_mask<<<1, 512, 0, stream>>>(counts, kbuck, mask, act, nact, inact, ninact);
  k_conv<<<dim3(32, 64, 32), 256, 0, stream>>>(x, kernels, act, nact, inact,
                                               ninact, out);
}